// Round 2
// baseline (151.862 us; speedup 1.0000x reference)
//
#include <hip/hip_runtime.h>
#include <hip/hip_fp16.h>

#define VOC    512
#define EMB    128
#define L_SEQ  32
#define NWORDS 16384
#define NCOL   416
#define WPB    128      // words per conv block
#define NSUB   13
#define SUBH   32       // global pe row width (halves)
#define ROWH   40       // LDS row pitch (halves) = 80 B -> bank-spread
#define SCP    40       // sc row pitch (u16)     = 80 B

// pe: 13 uniform subtables of 513 rows x 32 halves (row VOC=512 is all-zero):
//   sub 0    : seg0 (k2) 16 filters x jpad2
//   sub 1,2  : seg1 (k3) halves,   8 filters x jpad4
//   sub 3,4  : seg2 (k4) halves,   8 filters x jpad4
//   sub 5-8  : seg3 (k5) quarters, 4 filters x jpad8
//   sub 9-12 : seg4 (k6) quarters, 4 filters x jpad8

// -------- Kernel 1: fused pack+build, 2 chars per block (257 blocks) -----
__global__ __launch_bounds__(512) void build_pe(
    const float* __restrict__ emb,
    const float* __restrict__ w2, const float* __restrict__ w3,
    const float* __restrict__ w4, const float* __restrict__ w5,
    const float* __restrict__ w6,
    __half* __restrict__ pe)
{
    __shared__ float e[2][EMB];
    const int tid = threadIdx.x;
    const int c0  = blockIdx.x * 2;
    if (tid < 2 * EMB) {
        const int ch = tid >> 7, i = tid & 127, c = c0 + ch;
        e[ch][i] = (c < VOC) ? emb[c * EMB + i] : 0.f;   // c>=VOC -> zero row
    }
    __syncthreads();
    const int col = tid;
    if (col >= NCOL) return;

    int k, jpad, base, seg; const float* w;
    if (col < 32)       { k = 2; jpad = 2; base = 0;   seg = 0; w = w2; }
    else if (col < 96)  { k = 3; jpad = 4; base = 32;  seg = 1; w = w3; }
    else if (col < 160) { k = 4; jpad = 4; base = 96;  seg = 2; w = w4; }
    else if (col < 288) { k = 5; jpad = 8; base = 160; seg = 3; w = w5; }
    else                { k = 6; jpad = 8; base = 288; seg = 4; w = w6; }

    const int r  = col - base;
    const int ol = (jpad == 2) ? (r >> 1) : (jpad == 4) ? (r >> 2) : (r >> 3);
    const int j  = r & (jpad - 1);

    int sub, loc;
    if (seg == 0)      { sub = 0;           loc = ol * 2 + j; }
    else if (seg == 1) { sub = 1 + (ol>>3); loc = (ol & 7) * 4 + j; }
    else if (seg == 2) { sub = 3 + (ol>>3); loc = (ol & 7) * 4 + j; }
    else if (seg == 3) { sub = 5 + (ol>>2); loc = (ol & 3) * 8 + j; }
    else               { sub = 9 + (ol>>2); loc = (ol & 3) * 8 + j; }

    float a0 = 0.f, a1 = 0.f;
    if (j < k) {                            // padded taps stay zero
        const float* wp = w + (ol * EMB) * k + j;
        #pragma unroll 8
        for (int i = 0; i < EMB; ++i) {
            const float wv = wp[i * k];     // w[(ol*EMB+i)*k + j]
            a0 += wv * e[0][i]; a1 += wv * e[1][i];
        }
    }
    const int bb = sub * (513 * SUBH) + loc;
    pe[bb + c0 * SUBH] = __float2half(a0);
    if (c0 + 1 <= VOC) pe[bb + (c0 + 1) * SUBH] = __float2half(a1);
}

// -------- Kernel 2: LDS-resident uniform-subtable conv + max -------------
__device__ __forceinline__ float2 h2tof2(int u) {
    return __half22float2(__builtin_bit_cast(__half2, u));
}

// Ring-accumulator conv: K live accumulators, outputs retired into a running
// max as soon as their last tap lands. Bias added once at the end.
template<int K, int PAD, int NF, int JP>
__device__ __forceinline__ void convseg(
    const char* __restrict__ tbl,              // tab base + lane byte offset
    const unsigned short* __restrict__ sc,
    int w, float* __restrict__ mm)
{
    constexpr int LOUT = L_SEQ + 2 * PAD - K + 1;

    int d[16];
    {
        const int4* sp = (const int4*)(sc + w * SCP);   // 80B pitch, 16B aligned
        #pragma unroll
        for (int g = 0; g < 4; ++g) {
            const int4 s = sp[g];
            d[4*g] = s.x; d[4*g+1] = s.y; d[4*g+2] = s.z; d[4*g+3] = s.w;
        }
    }

    float ring[NF][K];
    float mx[NF];
    #pragma unroll
    for (int f = 0; f < NF; ++f) mx[f] = -3.0e38f;

    #pragma unroll
    for (int tp = 0; tp < 32; ++tp) {
        const int dw = d[tp >> 1];
        const int pm = (tp & 1) ? (int)(((unsigned)dw) >> 16) : (dw & 0xffff);
        float v[NF][JP];
        if constexpr (JP == 2) {                    // seg0: 2 filters, b64
            const int2 qq = *(const int2*)(tbl + pm);
            const float2 f0 = h2tof2(qq.x), f1 = h2tof2(qq.y);
            v[0][0]=f0.x; v[0][1]=f0.y; v[1][0]=f1.x; v[1][1]=f1.y;
        } else if constexpr (NF == 2) {             // seg1/2: 2 filters, b128
            const int4 qq = *(const int4*)(tbl + pm);
            const float2 a0=h2tof2(qq.x), a1=h2tof2(qq.y);
            const float2 c0=h2tof2(qq.z), c1=h2tof2(qq.w);
            v[0][0]=a0.x; v[0][1]=a0.y; v[0][2]=a1.x; v[0][3]=a1.y;
            v[1][0]=c0.x; v[1][1]=c0.y; v[1][2]=c1.x; v[1][3]=c1.y;
        } else {                                    // seg3/4: 1 filter, b128
            const int4 qq = *(const int4*)(tbl + pm);
            const float2 a0=h2tof2(qq.x), a1=h2tof2(qq.y), a2=h2tof2(qq.z);
            v[0][0]=a0.x; v[0][1]=a0.y; v[0][2]=a1.x; v[0][3]=a1.y;
            v[0][4]=a2.x;
            if constexpr (K >= 6) v[0][5]=a2.y;
        }
        #pragma unroll
        for (int j = 0; j < K; ++j) {
            const int t = tp + PAD - j;             // compile-time per (tp,j)
            if (t < 0 || t >= LOUT) continue;
            const bool first = (tp == ((t >= PAD) ? (t - PAD) : 0));
            #pragma unroll
            for (int f = 0; f < NF; ++f) {
                if (first) ring[f][t % K]  = v[f][j];
                else       ring[f][t % K] += v[f][j];
            }
        }
        const int tr = tp + PAD - (K - 1);          // output completed by tp
        if (tr >= 0 && tr < LOUT) {
            #pragma unroll
            for (int f = 0; f < NF; ++f)
                mx[f] = fmaxf(mx[f], ring[f][tr % K]);
        }
    }
    constexpr int TT = (32 + PAD - K + 1 > 0) ? (32 + PAD - K + 1) : 0;
    #pragma unroll
    for (int t = TT; t < LOUT; ++t)                 // tail (zero-pad region)
        #pragma unroll
        for (int f = 0; f < NF; ++f)
            mx[f] = fmaxf(mx[f], ring[f][t % K]);

    mm[0] = mx[0];
    if constexpr (NF == 2) mm[1] = mx[1];
}

__global__ __launch_bounds__(512, 6) void conv_max(
    const int*    __restrict__ word,
    const __half* __restrict__ pe,
    const float* __restrict__ b2, const float* __restrict__ b3,
    const float* __restrict__ b4, const float* __restrict__ b5,
    const float* __restrict__ b6,
    float*       __restrict__ out)
{
    // 41,040 B table + 10,240 B sc = 51,280 B -> 3 blocks/CU
    __shared__ __align__(16) __half tab[513 * ROWH];
    __shared__ __align__(16) unsigned short sc16[WPB * SCP];

    const int tid = threadIdx.x;
    const int sub = blockIdx.x % NSUB;     // block-uniform subtable
    const int wb  = blockIdx.x / NSUB;

    // stage subtable: 64B global rows -> 80B LDS rows (bank-spread)
    {
        const int4* src = (const int4*)(pe + sub * (513 * SUBH));
        char* tw = (char*)tab;
        for (int i = tid; i < 513 * 4; i += 512)
            *(int4*)(tw + (i >> 2) * 80 + (i & 3) * 16) = src[i];
    }
    // stage pre-multiplied row byte-offsets (c*80), row-major [word][SCP]
    {
        const int base = wb * (WPB * L_SEQ);
        #pragma unroll
        for (int r = 0; r < 8; ++r) {
            const int i = tid + r * 512;                // 0..4095
            const int c = word[base + i];               // coalesced
            const int ce = (c >= 0) ? c : VOC;
            sc16[(i >> 5) * SCP + (i & 31)] = (unsigned short)(ce * 80);
        }
    }
    __syncthreads();

    const char* tb    = (const char*)tab;
    const int   wbase = wb * WPB;

    int seg, q;
    if (sub == 0)     { seg = 0; q = 0; }
    else if (sub < 3) { seg = 1; q = sub - 1; }
    else if (sub < 5) { seg = 2; q = sub - 3; }
    else if (sub < 9) { seg = 3; q = sub - 5; }
    else              { seg = 4; q = sub - 9; }

    if (seg == 0) {
        // 8 filter-pairs x 64 words, 2 words/thread, b64 taps
        const int fp = tid & 7, w0 = tid >> 3;
        const char* tbl = tb + fp * 8;
        float m0[2], m1[2];
        convseg<2, 0, 2, 2>(tbl, sc16, w0,      m0);
        convseg<2, 0, 2, 2>(tbl, sc16, w0 + 64, m1);
        const float bb0 = b2[2*fp], bb1 = b2[2*fp + 1];
        float* o0 = out + (wbase + w0     ) * 80;
        float* o1 = out + (wbase + w0 + 64) * 80;
        o0[2*fp] = bb0 + m0[0]; o0[2*fp+1] = bb1 + m0[1];
        o1[2*fp] = bb0 + m1[0]; o1[2*fp+1] = bb1 + m1[1];
    } else if (seg <= 2) {
        // 4 filter-pairs x 128 words, 1 word/thread, b128 taps
        const int fp = tid & 3, w0 = tid >> 2;
        const char* tbl = tb + fp * 16;
        float m[2];
        if (seg == 1) convseg<3, 0, 2, 4>(tbl, sc16, w0, m);
        else          convseg<4, 1, 2, 4>(tbl, sc16, w0, m);
        const float* bp = (seg == 1) ? b3 : b4;
        const int f0 = q * 8 + 2 * fp;
        float* o = out + (wbase + w0) * 80 + seg * 16;
        o[f0]     = bp[f0]     + m[0];
        o[f0 + 1] = bp[f0 + 1] + m[1];
    } else {
        // 4 filters x 128 words, 1 word/thread, b128 taps
        const int ol = tid & 3, w0 = tid >> 2;
        const char* tbl = tb + ol * 16;
        float m[1];
        if (seg == 3) convseg<5, 2, 1, 8>(tbl, sc16, w0, m);
        else          convseg<6, 3, 1, 8>(tbl, sc16, w0, m);
        const float* bp = (seg == 3) ? b5 : b6;
        const int f = q * 4 + ol;
        out[(wbase + w0) * 80 + seg * 16 + f] = bp[f] + m[0];
    }
}

extern "C" void kernel_launch(void* const* d_in, const int* in_sizes, int n_in,
                              void* d_out, int out_size, void* d_ws, size_t ws_size,
                              hipStream_t stream)
{
    const int*   word = (const int*)  d_in[0];
    const float* emb  = (const float*)d_in[1];
    const float* w2   = (const float*)d_in[2];
    const float* b2   = (const float*)d_in[3];
    const float* w3   = (const float*)d_in[4];
    const float* b3   = (const float*)d_in[5];
    const float* w4   = (const float*)d_in[6];
    const float* b4   = (const float*)d_in[7];
    const float* w5   = (const float*)d_in[8];
    const float* b5   = (const float*)d_in[9];
    const float* w6   = (const float*)d_in[10];
    const float* b6   = (const float*)d_in[11];
    float* out = (float*)d_out;

    __half* pe16 = (__half*)d_ws;   // 13 * 513 * 32 halves = 426,816 B

    build_pe<<<257, 512, 0, stream>>>(emb, w2, w3, w4, w5, w6, pe16);

    conv_max<<<NSUB * (NWORDS / WPB), 512, 0, stream>>>(
        word, pe16, b2, b3, b4, b5, b6, out);
}

// Round 3
// 129.501 us; speedup vs baseline: 1.1727x; 1.1727x over previous
//
#include <hip/hip_runtime.h>
#include <hip/hip_fp16.h>

#define VOC    512
#define EMB    128
#define L_SEQ  32
#define NWORDS 16384
#define NCOL   416
#define WPB    64          // words per conv block
#define SUBW   32          // subtable row width (halves)
#define SUBSTRIDE_H 18432  // halves per subtable slice (2304 int4 = 9*256)
#define SCP    40          // sc row pitch in u16 (80 B)

// pe: 13 subtables, stride SUBSTRIDE_H halves, 513 rows x 32 halves each
// (row VOC=512 all-zero). Filter-pair INTERLEAVED layout for seg0/1/2:
//   seg0 (k2): sub 0,  loc = (ol>>1)*4 + j*2 + (ol&1)     (pairs of filters)
//   seg1 (k3): sub 1+(ol>>3), loc = ((ol&7)>>1)*8 + j*2 + (ol&1)
//   seg2 (k4): sub 3+(ol>>3), same loc formula
//   seg3 (k5): sub 5+(ol>>2), loc = (ol&3)*8 + j          (filter-major)
//   seg4 (k6): sub 9+(ol>>2), loc = (ol&3)*8 + j

// -------- Kernel 1: fused pack+build, 2 chars per block ------------------
__global__ __launch_bounds__(512) void build_pe(
    const float* __restrict__ emb,
    const float* __restrict__ w2, const float* __restrict__ w3,
    const float* __restrict__ w4, const float* __restrict__ w5,
    const float* __restrict__ w6,
    __half* __restrict__ pe)
{
    __shared__ float e[2][EMB];
    const int tid = threadIdx.x;
    const int c0  = blockIdx.x * 2;
    if (tid < 2 * EMB) {
        const int ch = tid >> 7, i = tid & 127, c = c0 + ch;
        e[ch][i] = (c < VOC) ? emb[c * EMB + i] : 0.f;   // c>=VOC -> zero row
    }
    __syncthreads();
    const int col = tid;
    if (col >= NCOL) return;

    int k, jpad, base, seg; const float* w;
    if (col < 32)       { k = 2; jpad = 2; base = 0;   seg = 0; w = w2; }
    else if (col < 96)  { k = 3; jpad = 4; base = 32;  seg = 1; w = w3; }
    else if (col < 160) { k = 4; jpad = 4; base = 96;  seg = 2; w = w4; }
    else if (col < 288) { k = 5; jpad = 8; base = 160; seg = 3; w = w5; }
    else                { k = 6; jpad = 8; base = 288; seg = 4; w = w6; }

    const int r  = col - base;
    const int ol = (jpad == 2) ? (r >> 1) : (jpad == 4) ? (r >> 2) : (r >> 3);
    const int j  = r & (jpad - 1);

    int sub, loc;
    if (seg == 0)      { sub = 0;           loc = (ol >> 1) * 4 + j * 2 + (ol & 1); }
    else if (seg == 1) { sub = 1 + (ol>>3); loc = ((ol & 7) >> 1) * 8 + j * 2 + (ol & 1); }
    else if (seg == 2) { sub = 3 + (ol>>3); loc = ((ol & 7) >> 1) * 8 + j * 2 + (ol & 1); }
    else if (seg == 3) { sub = 5 + (ol>>2); loc = (ol & 3) * 8 + j; }
    else               { sub = 9 + (ol>>2); loc = (ol & 3) * 8 + j; }

    float a0 = 0.f, a1 = 0.f;
    if (j < k) {                            // padded taps stay zero
        const float* wp = w + (ol * EMB) * k + j;
        #pragma unroll 8
        for (int i = 0; i < EMB; ++i) {
            const float wv = wp[i * k];     // w[(ol*EMB+i)*k + j]
            a0 += wv * e[0][i]; a1 += wv * e[1][i];
        }
    }
    const int bb = sub * SUBSTRIDE_H + loc;
    pe[bb + c0 * SUBW] = __float2half(a0);
    if (c0 + 1 <= VOC) pe[bb + (c0 + 1) * SUBW] = __float2half(a1);
}

// -------- Kernel 2: word-major blocks, subtables as phases ---------------
__device__ __forceinline__ float2 h2tof2(int u) {
    return __half22float2(__builtin_bit_cast(__half2, u));
}

// Paired ring conv: NP filter-pairs accumulated as float2, K-slot ring,
// outputs retired into running max when their last tap lands.
template<int K, int PAD, int NP>
__device__ __forceinline__ void convP(const char* __restrict__ tbl,
                                      const int* __restrict__ d,
                                      float2* __restrict__ mx)
{
    constexpr int LOUT = L_SEQ + 2 * PAD - K + 1;
    float2 ring[NP][K];
    #pragma unroll
    for (int p = 0; p < NP; ++p) mx[p] = make_float2(-3.0e38f, -3.0e38f);

    #pragma unroll
    for (int tp = 0; tp < 32; ++tp) {
        const int dw = d[tp >> 1];
        const int pm = (tp & 1) ? (int)(((unsigned)dw) >> 16) : (dw & 0xffff);
        const int4 qq = *(const int4*)(tbl + pm);
        const int W[4] = {qq.x, qq.y, qq.z, qq.w};
        #pragma unroll
        for (int w = 0; w < 4; ++w) {
            const int p = (NP == 2) ? (w >> 1) : 0;
            const int j = (NP == 2) ? (w & 1)  : w;
            if (j >= K) continue;                       // compile-time
            const int t = tp + PAD - j;
            if (t < 0 || t >= LOUT) continue;
            const float2 v = h2tof2(W[w]);
            if (tp == ((t >= PAD) ? (t - PAD) : 0)) {   // first contributor
                ring[p][t % K] = v;
            } else {
                ring[p][t % K].x += v.x;
                ring[p][t % K].y += v.y;
            }
        }
        const int tr = tp + PAD - (K - 1);              // completed output
        if (tr >= 0 && tr < LOUT) {
            #pragma unroll
            for (int p = 0; p < NP; ++p) {
                mx[p].x = fmaxf(mx[p].x, ring[p][tr % K].x);
                mx[p].y = fmaxf(mx[p].y, ring[p][tr % K].y);
            }
        }
    }
    #pragma unroll
    for (int t = 32 + PAD - K + 1; t < LOUT; ++t)       // tail (pad region)
        #pragma unroll
        for (int p = 0; p < NP; ++p) {
            mx[p].x = fmaxf(mx[p].x, ring[p][t % K].x);
            mx[p].y = fmaxf(mx[p].y, ring[p][t % K].y);
        }
}

// Scalar ring conv: one filter, halves j0..7 in the b128.
template<int K, int PAD>
__device__ __forceinline__ float convS(const char* __restrict__ tbl,
                                       const int* __restrict__ d)
{
    constexpr int LOUT = L_SEQ + 2 * PAD - K + 1;
    float ring[K];
    float mx = -3.0e38f;
    #pragma unroll
    for (int tp = 0; tp < 32; ++tp) {
        const int dw = d[tp >> 1];
        const int pm = (tp & 1) ? (int)(((unsigned)dw) >> 16) : (dw & 0xffff);
        const int4 qq = *(const int4*)(tbl + pm);
        const int W[4] = {qq.x, qq.y, qq.z, qq.w};
        float v[K];
        #pragma unroll
        for (int w = 0; w < (K + 1) / 2; ++w) {
            const float2 f = h2tof2(W[w]);
            v[2 * w] = f.x;
            if (2 * w + 1 < K) v[2 * w + 1] = f.y;
        }
        #pragma unroll
        for (int j = 0; j < K; ++j) {
            const int t = tp + PAD - j;
            if (t < 0 || t >= LOUT) continue;
            if (tp == ((t >= PAD) ? (t - PAD) : 0)) ring[t % K]  = v[j];
            else                                    ring[t % K] += v[j];
        }
        const int tr = tp + PAD - (K - 1);
        if (tr >= 0 && tr < LOUT) mx = fmaxf(mx, ring[tr % K]);
    }
    #pragma unroll
    for (int t = 32 + PAD - K + 1; t < LOUT; ++t) mx = fmaxf(mx, ring[t % K]);
    return mx;
}

__global__ __launch_bounds__(256, 3) void conv_max(
    const int*    __restrict__ word,
    const __half* __restrict__ pe,
    const float* __restrict__ b2, const float* __restrict__ b3,
    const float* __restrict__ b4, const float* __restrict__ b5,
    const float* __restrict__ b6,
    float*       __restrict__ out)
{
    // 46,080 B table (576 rows x 80 B, rows >512 = staging pad, never read)
    // + 5,120 B sc = 51,200 B -> up to 3 blocks/CU
    __shared__ __align__(16) __half tab[576 * 40];
    __shared__ __align__(16) unsigned short sc16[WPB * SCP];

    const int tid = threadIdx.x;
    const int g   = blockIdx.x >> 8;       // group: 0 -> subs 0..5, 1 -> 6..12
    const int wb  = blockIdx.x & 255;      // word-block; g stride 256 ≡ 0 mod 8
                                           // -> both groups of wb on same XCD
    int4 P[9];                             // prefetch regs (2304 int4 / 256 thr)
    auto pref = [&](int s) {
        const int4* sp = (const int4*)(pe + s * SUBSTRIDE_H);
        #pragma unroll
        for (int r = 0; r < 9; ++r) P[r] = sp[tid + r * 256];
    };
    auto dsw = [&]() {                     // regs -> LDS, 64B rows @ 80B pitch
        char* tw = (char*)tab;
        #pragma unroll
        for (int r = 0; r < 9; ++r) {
            const int i = tid + r * 256;
            *(int4*)(tw + (i >> 2) * 80 + (i & 3) * 16) = P[r];
        }
    };

    pref(g == 0 ? 0 : 6);                  // first subtable in flight

    {   // stage pre-multiplied row byte-offsets (c*80) once per block
        const int base = wb * (WPB * L_SEQ);
        #pragma unroll
        for (int r = 0; r < 8; ++r) {
            const int i = tid + r * 256;                // 0..2047
            const int c = word[base + i];               // coalesced
            const int ce = (c >= 0) ? c : VOC;
            sc16[(i >> 5) * SCP + (i & 31)] = (unsigned short)(ce * 80);
        }
    }
    __syncthreads();

    const int q = tid & 3, w = tid >> 2;   // 4 threads per word
    int d[16];                             // word's 32 tap offsets, read ONCE
    {
        const int4* sp = (const int4*)(sc16 + w * SCP);
        #pragma unroll
        for (int gg = 0; gg < 4; ++gg) {
            const int4 s = sp[gg];
            d[4*gg] = s.x; d[4*gg+1] = s.y; d[4*gg+2] = s.z; d[4*gg+3] = s.w;
        }
    }
    dsw(); __syncthreads();                // first subtable ready

    const char* tbl = (const char*)tab + q * 16;
    const int   wo  = (wb * WPB + w) * 80;

    if (g == 0) {
        float2 m0[2], m1a[1], m1b[1], m2a[1], m2b[1];
        pref(1); convP<2,0,2>(tbl, d, m0);  __syncthreads(); dsw(); __syncthreads();
        pref(2); convP<3,0,1>(tbl, d, m1a); __syncthreads(); dsw(); __syncthreads();
        pref(3); convP<3,0,1>(tbl, d, m1b); __syncthreads(); dsw(); __syncthreads();
        pref(4); convP<4,1,1>(tbl, d, m2a); __syncthreads(); dsw(); __syncthreads();
        pref(5); convP<4,1,1>(tbl, d, m2b); __syncthreads(); dsw(); __syncthreads();
        const float m3 = convS<5,2>(tbl, d);

        float4 o4;
        o4.x = m0[0].x + b2[4*q];   o4.y = m0[0].y + b2[4*q+1];
        o4.z = m0[1].x + b2[4*q+2]; o4.w = m0[1].y + b2[4*q+3];
        *(float4*)(out + wo + 4*q) = o4;
        float2 o2;
        o2.x = m1a[0].x + b3[2*q];   o2.y = m1a[0].y + b3[2*q+1];
        *(float2*)(out + wo + 16 + 2*q) = o2;
        o2.x = m1b[0].x + b3[8+2*q]; o2.y = m1b[0].y + b3[8+2*q+1];
        *(float2*)(out + wo + 24 + 2*q) = o2;
        o2.x = m2a[0].x + b4[2*q];   o2.y = m2a[0].y + b4[2*q+1];
        *(float2*)(out + wo + 32 + 2*q) = o2;
        o2.x = m2b[0].x + b4[8+2*q]; o2.y = m2b[0].y + b4[8+2*q+1];
        *(float2*)(out + wo + 40 + 2*q) = o2;
        out[wo + 48 + q] = m3 + b5[q];
    } else {
        pref(7);  const float s6  = convS<5,2>(tbl, d); __syncthreads(); dsw(); __syncthreads();
        pref(8);  const float s7  = convS<5,2>(tbl, d); __syncthreads(); dsw(); __syncthreads();
        pref(9);  const float s8  = convS<5,2>(tbl, d); __syncthreads(); dsw(); __syncthreads();
        pref(10); const float s9  = convS<6,3>(tbl, d); __syncthreads(); dsw(); __syncthreads();
        pref(11); const float s10 = convS<6,3>(tbl, d); __syncthreads(); dsw(); __syncthreads();
        pref(12); const float s11 = convS<6,3>(tbl, d); __syncthreads(); dsw(); __syncthreads();
        const float s12 = convS<6,3>(tbl, d);

        out[wo + 52 + q] = s6  + b5[4+q];
        out[wo + 56 + q] = s7  + b5[8+q];
        out[wo + 60 + q] = s8  + b5[12+q];
        out[wo + 64 + q] = s9  + b6[q];
        out[wo + 68 + q] = s10 + b6[4+q];
        out[wo + 72 + q] = s11 + b6[8+q];
        out[wo + 76 + q] = s12 + b6[12+q];
    }
}

extern "C" void kernel_launch(void* const* d_in, const int* in_sizes, int n_in,
                              void* d_out, int out_size, void* d_ws, size_t ws_size,
                              hipStream_t stream)
{
    const int*   word = (const int*)  d_in[0];
    const float* emb  = (const float*)d_in[1];
    const float* w2   = (const float*)d_in[2];
    const float* b2   = (const float*)d_in[3];
    const float* w3   = (const float*)d_in[4];
    const float* b3   = (const float*)d_in[5];
    const float* w4   = (const float*)d_in[6];
    const float* b4   = (const float*)d_in[7];
    const float* w5   = (const float*)d_in[8];
    const float* b5   = (const float*)d_in[9];
    const float* w6   = (const float*)d_in[10];
    const float* b6   = (const float*)d_in[11];
    float* out = (float*)d_out;

    __half* pe16 = (__half*)d_ws;   // 13 * 18432 halves = 479,232 B

    build_pe<<<257, 512, 0, stream>>>(emb, w2, w3, w4, w5, w6, pe16);

    conv_max<<<512, 256, 0, stream>>>(
        word, pe16, b2, b3, b4, b5, b6, out);
}

// Round 4
// 108.283 us; speedup vs baseline: 1.4025x; 1.1960x over previous
//
#include <hip/hip_runtime.h>
#include <hip/hip_fp16.h>

#define VOC    512
#define EMB    128
#define L_SEQ  32
#define NWORDS 16384
#define NCOL   416
#define WPB    128         // words per conv block
#define SUBW   32          // subtable row width (halves)
#define SUBSTRIDE_H 16416  // 513*32 halves per subtable
#define SCP    40          // sc row pitch in u16 (80 B)

// pe: 13 subtables of 513 rows x 32 halves (row VOC=512 all-zero).
// Filter-pair INTERLEAVED layout for segs 0-2 (packed float2 accumulation):
//   seg0 (k2): sub 0,  loc = (ol>>1)*4 + j*2 + (ol&1)
//   seg1 (k3): sub 1+(ol>>3), loc = ((ol&7)>>1)*8 + j*2 + (ol&1)
//   seg2 (k4): sub 3+(ol>>3), same formula
//   seg3 (k5): sub 5+(ol>>2), loc = (ol&3)*8 + j   (filter-major)
//   seg4 (k6): sub 9+(ol>>2), loc = (ol&3)*8 + j

// -------- Kernel 1: fused pack+build, 2 chars per block ------------------
__global__ __launch_bounds__(512) void build_pe(
    const float* __restrict__ emb,
    const float* __restrict__ w2, const float* __restrict__ w3,
    const float* __restrict__ w4, const float* __restrict__ w5,
    const float* __restrict__ w6,
    __half* __restrict__ pe)
{
    __shared__ float e[2][EMB];
    const int tid = threadIdx.x;
    const int c0  = blockIdx.x * 2;
    if (tid < 2 * EMB) {
        const int ch = tid >> 7, i = tid & 127, c = c0 + ch;
        e[ch][i] = (c < VOC) ? emb[c * EMB + i] : 0.f;   // c>=VOC -> zero row
    }
    __syncthreads();
    const int col = tid;
    if (col >= NCOL) return;

    int k, jpad, base, seg; const float* w;
    if (col < 32)       { k = 2; jpad = 2; base = 0;   seg = 0; w = w2; }
    else if (col < 96)  { k = 3; jpad = 4; base = 32;  seg = 1; w = w3; }
    else if (col < 160) { k = 4; jpad = 4; base = 96;  seg = 2; w = w4; }
    else if (col < 288) { k = 5; jpad = 8; base = 160; seg = 3; w = w5; }
    else                { k = 6; jpad = 8; base = 288; seg = 4; w = w6; }

    const int r  = col - base;
    const int ol = (jpad == 2) ? (r >> 1) : (jpad == 4) ? (r >> 2) : (r >> 3);
    const int j  = r & (jpad - 1);

    int sub, loc;
    if (seg == 0)      { sub = 0;           loc = (ol >> 1) * 4 + j * 2 + (ol & 1); }
    else if (seg == 1) { sub = 1 + (ol>>3); loc = ((ol & 7) >> 1) * 8 + j * 2 + (ol & 1); }
    else if (seg == 2) { sub = 3 + (ol>>3); loc = ((ol & 7) >> 1) * 8 + j * 2 + (ol & 1); }
    else if (seg == 3) { sub = 5 + (ol>>2); loc = (ol & 3) * 8 + j; }
    else               { sub = 9 + (ol>>2); loc = (ol & 3) * 8 + j; }

    float a0 = 0.f, a1 = 0.f;
    if (j < k) {                            // padded taps stay zero
        const float* wp = w + (ol * EMB) * k + j;
        #pragma unroll 8
        for (int i = 0; i < EMB; ++i) {
            const float wv = wp[i * k];     // w[(ol*EMB+i)*k + j]
            a0 += wv * e[0][i]; a1 += wv * e[1][i];
        }
    }
    const int bb = sub * SUBSTRIDE_H + loc;
    pe[bb + c0 * SUBW] = __float2half(a0);
    if (c0 + 1 <= VOC) pe[bb + (c0 + 1) * SUBW] = __float2half(a1);
}

// -------- Kernel 2: sub-split blocks, XCD-co-located word groups ---------
__device__ __forceinline__ float2 h2tof2(int u) {
    return __half22float2(__builtin_bit_cast(__half2, u));
}

// Paired conv: flat bias-initialized float2 accumulators (2 filters).
template<int K, int PAD>
__device__ __forceinline__ float2 convP(const char* __restrict__ tbl,
                                        const unsigned short* __restrict__ sc,
                                        int w, float2 bias)
{
    constexpr int LOUT = L_SEQ + 2 * PAD - K + 1;
    int d[16];
    {
        const int4* sp = (const int4*)(sc + w * SCP);   // 80B pitch, aligned
        #pragma unroll
        for (int g = 0; g < 4; ++g) {
            const int4 s4 = sp[g];
            d[4*g] = s4.x; d[4*g+1] = s4.y; d[4*g+2] = s4.z; d[4*g+3] = s4.w;
        }
    }
    float2 s[LOUT];
    #pragma unroll
    for (int t = 0; t < LOUT; ++t) s[t] = bias;

    #pragma unroll
    for (int tp = 0; tp < 32; ++tp) {
        const int dw = d[tp >> 1];
        const int pm = (tp & 1) ? (int)(((unsigned)dw) >> 16) : (dw & 0xffff);
        if constexpr (K == 2) {
            const int2 qq = *(const int2*)(tbl + pm);
            const int W2[2] = {qq.x, qq.y};
            #pragma unroll
            for (int j = 0; j < 2; ++j) {
                const int t = tp - j;                   // PAD=0
                if (t >= 0 && t < LOUT) {
                    const float2 v = h2tof2(W2[j]);
                    s[t].x += v.x; s[t].y += v.y;
                }
            }
        } else {
            const int4 qq = *(const int4*)(tbl + pm);
            const int W4[4] = {qq.x, qq.y, qq.z, qq.w};
            #pragma unroll
            for (int j = 0; j < K; ++j) {               // K<=4 here
                const int t = tp + PAD - j;
                if (t >= 0 && t < LOUT) {
                    const float2 v = h2tof2(W4[j]);
                    s[t].x += v.x; s[t].y += v.y;
                }
            }
        }
    }
    float2 m = s[0];
    #pragma unroll
    for (int t = 1; t < LOUT; ++t) {
        m.x = fmaxf(m.x, s[t].x); m.y = fmaxf(m.y, s[t].y);
    }
    return m;
}

// Scalar conv: one filter, flat bias-initialized accumulators.
template<int K, int PAD>
__device__ __forceinline__ float convS(const char* __restrict__ tbl,
                                       const unsigned short* __restrict__ sc,
                                       int w, float bias)
{
    constexpr int LOUT = L_SEQ + 2 * PAD - K + 1;
    int d[16];
    {
        const int4* sp = (const int4*)(sc + w * SCP);
        #pragma unroll
        for (int g = 0; g < 4; ++g) {
            const int4 s4 = sp[g];
            d[4*g] = s4.x; d[4*g+1] = s4.y; d[4*g+2] = s4.z; d[4*g+3] = s4.w;
        }
    }
    float s[LOUT];
    #pragma unroll
    for (int t = 0; t < LOUT; ++t) s[t] = bias;

    #pragma unroll
    for (int tp = 0; tp < 32; ++tp) {
        const int dw = d[tp >> 1];
        const int pm = (tp & 1) ? (int)(((unsigned)dw) >> 16) : (dw & 0xffff);
        const int4 qq = *(const int4*)(tbl + pm);
        const int W4[4] = {qq.x, qq.y, qq.z, qq.w};
        float v[K];
        #pragma unroll
        for (int h = 0; h < (K + 1) / 2; ++h) {
            const float2 f = h2tof2(W4[h]);
            v[2*h] = f.x;
            if (2*h + 1 < K) v[2*h + 1] = f.y;
        }
        #pragma unroll
        for (int j = 0; j < K; ++j) {
            const int t = tp + PAD - j;
            if (t >= 0 && t < LOUT) s[t] += v[j];
        }
    }
    float m = s[0];
    #pragma unroll
    for (int t = 1; t < LOUT; ++t) m = fmaxf(m, s[t]);
    return m;
}

__global__ __launch_bounds__(512, 4) void conv_max(
    const int*    __restrict__ word,
    const __half* __restrict__ pe,
    const float* __restrict__ b2, const float* __restrict__ b3,
    const float* __restrict__ b4, const float* __restrict__ b5,
    const float* __restrict__ b6,
    float*       __restrict__ out)
{
    // 41,040 B table (513 x 80 B pitch) + 10,240 B sc = 51,280 B
    __shared__ __align__(16) __half tab[513 * 40];
    __shared__ __align__(16) unsigned short sc16[WPB * SCP];

    const int tid = threadIdx.x;
    const int wb  = blockIdx.x & 127;   // word group; XCD = wb%8
    const int sub = blockIdx.x >> 7;    // 0..12 -> SAME XCD for all subs of wb

    // stage subtable: 64B global rows -> 80B LDS pitch (bank-spread)
    {
        const int4* src = (const int4*)(pe + sub * SUBSTRIDE_H);
        char* tw = (char*)tab;
        for (int i = tid; i < 513 * 4; i += 512)
            *(int4*)(tw + (i >> 2) * 80 + (i & 3) * 16) = src[i];
    }
    // stage pre-multiplied row byte-offsets (c*80), row-major [word][SCP]
    {
        const int base = wb * (WPB * L_SEQ);
        #pragma unroll
        for (int r = 0; r < 8; ++r) {
            const int i = tid + r * 512;                // 0..4095
            const int c = word[base + i];               // coalesced
            const int ce = (c >= 0) ? c : VOC;
            sc16[(i >> 5) * SCP + (i & 31)] = (unsigned short)(ce * 80);
        }
    }
    __syncthreads();

    const char* tb = (const char*)tab;
    float* ob = out + wb * (WPB * 80);

    if (sub == 0) {
        // 8 filter-pairs x 64 words, 2 words/thread, b64 taps
        const int p = tid & 7, w = tid >> 3;
        const char* tbl = tb + p * 8;
        const float2 bias = {b2[2*p], b2[2*p + 1]};
        const float2 ma = convP<2, 0>(tbl, sc16, w,      bias);
        const float2 mb = convP<2, 0>(tbl, sc16, w + 64, bias);
        *(float2*)(ob + w * 80 + 2*p)        = ma;
        *(float2*)(ob + (w + 64) * 80 + 2*p) = mb;
    } else if (sub <= 4) {
        // 4 filter-pairs x 128 words, 1 word/thread, b128 taps
        const int fp = tid & 3, w = tid >> 2;
        const char* tbl = tb + fp * 16;
        const int half = (sub - 1) & 1;
        const bool is1 = (sub <= 2);
        const float* bp = is1 ? b3 : b4;
        const int f0 = half * 8 + 2 * fp;
        const float2 bias = {bp[f0], bp[f0 + 1]};
        float2 m;
        if (is1) m = convP<3, 0>(tbl, sc16, w, bias);
        else     m = convP<4, 1>(tbl, sc16, w, bias);
        const int oo = (is1 ? 16 : 32) + f0;
        *(float2*)(ob + w * 80 + oo) = m;
    } else if (sub <= 8) {
        // seg3 (k5): 4 filters x 128 words
        const int ol = tid & 3, w = tid >> 2;
        const char* tbl = tb + ol * 16;
        const int f = (sub - 5) * 4 + ol;
        const float m = convS<5, 2>(tbl, sc16, w, b5[f]);
        ob[w * 80 + 48 + f] = m;
    } else {
        // seg4 (k6): 4 filters x 128 words
        const int ol = tid & 3, w = tid >> 2;
        const char* tbl = tb + ol * 16;
        const int f = (sub - 9) * 4 + ol;
        const float m = convS<6, 3>(tbl, sc16, w, b6[f]);
        ob[w * 80 + 64 + f] = m;
    }
}

extern "C" void kernel_launch(void* const* d_in, const int* in_sizes, int n_in,
                              void* d_out, int out_size, void* d_ws, size_t ws_size,
                              hipStream_t stream)
{
    const int*   word = (const int*)  d_in[0];
    const float* emb  = (const float*)d_in[1];
    const float* w2   = (const float*)d_in[2];
    const float* b2   = (const float*)d_in[3];
    const float* w3   = (const float*)d_in[4];
    const float* b3   = (const float*)d_in[5];
    const float* w4   = (const float*)d_in[6];
    const float* b4   = (const float*)d_in[7];
    const float* w5   = (const float*)d_in[8];
    const float* b5   = (const float*)d_in[9];
    const float* w6   = (const float*)d_in[10];
    const float* b6   = (const float*)d_in[11];
    float* out = (float*)d_out;

    __half* pe16 = (__half*)d_ws;   // 13 * 16416 halves = 426,816 B

    build_pe<<<257, 512, 0, stream>>>(emb, w2, w3, w4, w5, w6, pe16);

    conv_max<<<13 * 128, 512, 0, stream>>>(
        word, pe16, b2, b3, b4, b5, b6, out);
}